// Round 17
// baseline (159.732 us; speedup 1.0000x reference)
//
#include <hip/hip_runtime.h>
#include <hip/hip_bf16.h>
#include <cstdint>
#include <cstddef>

#define D_MODEL 1024
#define SEQ_N   4096
#define BATCH   2
#define BAND    192   // 3 x 64-col window [g*64-64, g*64+128) per 64-row group g (+-64 coverage)
#define NELEM   ((size_t)BATCH * SEQ_N * D_MODEL)   // 8388608

typedef __attribute__((ext_vector_type(4))) float  floatx4;
typedef __attribute__((ext_vector_type(8))) short  short8;
typedef __attribute__((ext_vector_type(4))) short  short4v;

__device__ __forceinline__ unsigned short f2bf(float f) {
  unsigned u = __float_as_uint(f);
  u += 0x7FFFu + ((u >> 16) & 1u);   // round-to-nearest-even
  return (unsigned short)(u >> 16);
}
__device__ __forceinline__ float bf2f(unsigned short u) {
  return __uint_as_float(((unsigned)u) << 16);
}

// ---- fused prep: x->xb, Wv->Bcat2 hi (bf16), Wq/Wk -> transposed bf16, K1d, bv bias ----
__global__ __launch_bounds__(256)
void fused_prep(const float* __restrict__ x,
                const float* __restrict__ Wq, const float* __restrict__ Wk,
                const float* __restrict__ Wv, const float* __restrict__ bv,
                const float* __restrict__ alpha_p, const float* __restrict__ lam_p,
                unsigned short* __restrict__ xb,
                unsigned short* __restrict__ Bcat2,   // [2048][1024]; rows 1024.. = Wv bf16
                unsigned short* __restrict__ wqT,     // [1024][1024] = Wq^T bf16
                unsigned short* __restrict__ wkT,     // [1024][1024] = Wk^T bf16
                float* __restrict__ bias2,            // [2048]; hi half = bv
                float* __restrict__ K1d)
{
  __shared__ unsigned short Tld[64][66];
  int bid = blockIdx.x, tid = threadIdx.x;
  if (bid < 4096) {                       // x -> xb
    int i = bid * 256 + tid;
    const floatx4* s4 = (const floatx4*)x;
    floatx4 a = s4[i * 2], b = s4[i * 2 + 1];
    short8 pk;
    pk[0] = (short)f2bf(a[0]); pk[1] = (short)f2bf(a[1]);
    pk[2] = (short)f2bf(a[2]); pk[3] = (short)f2bf(a[3]);
    pk[4] = (short)f2bf(b[0]); pk[5] = (short)f2bf(b[1]);
    pk[6] = (short)f2bf(b[2]); pk[7] = (short)f2bf(b[3]);
    *(short8*)(xb + (size_t)i * 8) = pk;
  } else if (bid < 4608) {                // Wv -> Bcat2 rows 1024..2047
    int i = (bid - 4096) * 256 + tid;     // < 131072
    const floatx4* s4 = (const floatx4*)Wv;
    floatx4 a = s4[i * 2], b = s4[i * 2 + 1];
    short8 pk;
    pk[0] = (short)f2bf(a[0]); pk[1] = (short)f2bf(a[1]);
    pk[2] = (short)f2bf(a[2]); pk[3] = (short)f2bf(a[3]);
    pk[4] = (short)f2bf(b[0]); pk[5] = (short)f2bf(b[1]);
    pk[6] = (short)f2bf(b[2]); pk[7] = (short)f2bf(b[3]);
    *(short8*)(Bcat2 + (size_t)D_MODEL * D_MODEL + (size_t)i * 8) = pk;
  } else if (bid < 5120) {                // transpose Wq / Wk -> bf16
    int u = bid - 4608;                   // 0..511
    const float* src = (u < 256) ? Wq : Wk;
    unsigned short* dst = (u < 256) ? wqT : wkT;
    int t = u & 255;
    int tr = t >> 4, tc = t & 15;         // 64x64 tile (tr,tc)
    int rl = tid >> 2, cc = (tid & 3) * 16;
    const float* sp = src + (size_t)(tr * 64 + rl) * D_MODEL + tc * 64 + cc;
#pragma unroll
    for (int q4 = 0; q4 < 4; ++q4) {
      floatx4 v = *(const floatx4*)(sp + q4 * 4);
#pragma unroll
      for (int e = 0; e < 4; ++e) Tld[cc + q4 * 4 + e][rl] = f2bf(v[e]);
    }
    __syncthreads();
    int cl = tid >> 2, rchunk = (tid & 3) * 16;
    short8 o0, o1;
#pragma unroll
    for (int e = 0; e < 8; ++e) { o0[e] = (short)Tld[cl][rchunk + e]; o1[e] = (short)Tld[cl][rchunk + 8 + e]; }
    unsigned short* dp = dst + (size_t)(tc * 64 + cl) * D_MODEL + tr * 64 + rchunk;
    *(short8*)dp = o0;
    *(short8*)(dp + 8) = o1;
  } else {                                // K1d + bv bias
    int t = (bid - 5120) * 256 + tid;     // 0..5119
    if (t < SEQ_N) {
      float a   = fabsf(alpha_p[0]);
      float lam = fabsf(lam_p[0]);
      float rf  = (float)t;
      K1d[t] = powf(rf + 1e-4f, -a) * expf(-rf / lam);
    }
    int v = t - SEQ_N;
    if (v >= 0 && v < D_MODEL) bias2[D_MODEL + v] = bv[v];
  }
}

// ---- vwm_kernel: {v-gemm (bid<512) | wtilde (512..1024) | Mt gemm (1024..1280)} ----
// v-gemm: out cols 1024..2047 of x@Bcat2^T -> vT transposed (+bv); depends on prep only.
__global__ __launch_bounds__(256)
void vwm_kernel(const unsigned short* __restrict__ xb,
                const unsigned short* __restrict__ Bcat2,
                unsigned short* __restrict__ vT,
                const unsigned short* __restrict__ wkT,
                const unsigned short* __restrict__ wqT,
                const float* __restrict__ bq, const float* __restrict__ bk,
                unsigned short* __restrict__ Mt,      // = Bcat2 rows 0..1023
                float* __restrict__ bias2,            // lo written (w~k), hi read (bv)
                float* __restrict__ wqv)
{
  __shared__ unsigned short As[128 * 64];
  __shared__ unsigned short Bs[128 * 64];
  const int bid = blockIdx.x, tid = threadIdx.x;
  const int lane = tid & 63, wave = tid >> 6;

  if (bid >= 1024) {
    // ---- Mt = wkT (bt) wqT, 64x64 tiles (256 blocks); reuse As/Bs prefix as [64*32] ----
    int flat = bid - 1024;
    int w = (flat & 7) * 32 + (flat >> 3);
    int bx = w % 16, by = w / 16;
    const int bm0 = by * 64, bn0 = bx * 64;
    const int wm = (wave >> 1) * 32, wn = (wave & 1) * 32;

    floatx4 acc[2][2] = {};
    for (int k0 = 0; k0 < D_MODEL; k0 += 32) {
      {
        int bu = wave * 64;
        int u  = bu + lane;
        const unsigned short* srcA = wkT + (size_t)(bm0 + (u >> 2)) * D_MODEL + k0 + (u & 3) * 8;
        __builtin_amdgcn_global_load_lds((const __attribute__((address_space(1))) void*)srcA,
                                         (__attribute__((address_space(3))) void*)(As + bu * 8), 16, 0, 0);
        const unsigned short* srcB = wqT + (size_t)(bn0 + (u >> 2)) * D_MODEL + k0 + (u & 3) * 8;
        __builtin_amdgcn_global_load_lds((const __attribute__((address_space(1))) void*)srcB,
                                         (__attribute__((address_space(3))) void*)(Bs + bu * 8), 16, 0, 0);
      }
      __syncthreads();
      short8 af[2], bf[2];
#pragma unroll
      for (int i = 0; i < 2; ++i)
        af[i] = *(const short8*)(As + (wm + i * 16 + (lane & 15)) * 32 + (lane >> 4) * 8);
#pragma unroll
      for (int j = 0; j < 2; ++j)
        bf[j] = *(const short8*)(Bs + (wn + j * 16 + (lane & 15)) * 32 + (lane >> 4) * 8);
#pragma unroll
      for (int i = 0; i < 2; ++i)
#pragma unroll
        for (int j = 0; j < 2; ++j)
          acc[i][j] = __builtin_amdgcn_mfma_f32_16x16x32_bf16(af[i], bf[j], acc[i][j], 0, 0, 0);
      __syncthreads();
    }
#pragma unroll
    for (int i = 0; i < 2; ++i) {
#pragma unroll
      for (int j = 0; j < 2; ++j) {
        int col   = bn0 + wn + j * 16 + (lane & 15);
        int rbase = bm0 + wm + i * 16 + (lane >> 4) * 4;
#pragma unroll
        for (int r = 0; r < 4; ++r)
          Mt[(size_t)(rbase + r) * D_MODEL + col] = f2bf(acc[i][j][r]);
      }
    }
    return;
  }

  if (bid >= 512) {
    // ---- wtilde: bias2[d]=wkT[d].bq for idx<1024; wqv[d]=wqT[d].bk otherwise ----
    const int idx = (bid - 512) * 4 + wave;   // 0..2047
    const int d = idx & (D_MODEL - 1);
    const bool isK = idx < D_MODEL;
    const unsigned short* row = (isK ? wkT : wqT) + (size_t)d * D_MODEL + lane * 16;
    const float* b = isK ? bq : bk;
    float s = 0.f;
    short8 v0 = *(const short8*)row, v1 = *(const short8*)(row + 8);
#pragma unroll
    for (int e = 0; e < 8; ++e) {
      s += bf2f((unsigned short)v0[e]) * b[lane * 16 + e];
      s += bf2f((unsigned short)v1[e]) * b[lane * 16 + 8 + e];
    }
#pragma unroll
    for (int o = 32; o; o >>= 1) s += __shfl_xor(s, o);
    if (lane == 0) { if (isK) bias2[d] = s; else wqv[d] = s; }
    return;
  }

  // ---- v-gemm: 512 blocks; XCD swizzle over 512; BK=64 + chunk-XOR swizzle ----
  int flat = bid;
  int w    = (flat & 7) * 64 + (flat >> 3);
  int bx = w & 7, by = w >> 3;
  const int bm0 = by * 128;                 // x row
  const int bn0 = D_MODEL + bx * 128;       // Bcat2 row (v col + 1024)
  const int wm = (wave >> 1) * 64, wn = (wave & 1) * 64;

  floatx4 acc[4][4] = {};
  for (int k0 = 0; k0 < D_MODEL; k0 += 64) {
#pragma unroll
    for (int t = 0; t < 4; ++t) {
      int bu  = wave * 64 + t * 256;
      int u   = bu + lane;
      int row = u >> 3;
      int c   = (u & 7) ^ (row & 7);
      const unsigned short* srcA = xb + (size_t)(bm0 + row) * D_MODEL + k0 + c * 8;
      __builtin_amdgcn_global_load_lds((const __attribute__((address_space(1))) void*)srcA,
                                       (__attribute__((address_space(3))) void*)(As + bu * 8), 16, 0, 0);
      const unsigned short* srcB = Bcat2 + (size_t)(bn0 + row) * D_MODEL + k0 + c * 8;
      __builtin_amdgcn_global_load_lds((const __attribute__((address_space(1))) void*)srcB,
                                       (__attribute__((address_space(3))) void*)(Bs + bu * 8), 16, 0, 0);
    }
    __syncthreads();
#pragma unroll
    for (int s = 0; s < 2; ++s) {
      short8 af[4], bf[4];
#pragma unroll
      for (int i = 0; i < 4; ++i) {
        int row = wm + i * 16 + (lane & 15);
        int pc  = (s * 4 + (lane >> 4)) ^ (row & 7);
        af[i] = *(const short8*)(As + row * 64 + pc * 8);
      }
#pragma unroll
      for (int j = 0; j < 4; ++j) {
        int row = wn + j * 16 + (lane & 15);
        int pc  = (s * 4 + (lane >> 4)) ^ (row & 7);
        bf[j] = *(const short8*)(Bs + row * 64 + pc * 8);
      }
#pragma unroll
      for (int i = 0; i < 4; ++i)
#pragma unroll
        for (int j = 0; j < 4; ++j)
          acc[i][j] = __builtin_amdgcn_mfma_f32_16x16x32_bf16(af[i], bf[j], acc[i][j], 0, 0, 0);
    }
    __syncthreads();
  }

#pragma unroll
  for (int i = 0; i < 4; ++i) {
#pragma unroll
    for (int j = 0; j < 4; ++j) {
      int n     = bn0 + wn + j * 16 + (lane & 15);
      int e     = n - D_MODEL;
      int rbase = bm0 + wm + i * 16 + (lane >> 4) * 4;
      float b = bias2[n];
      short4v pk;
#pragma unroll
      for (int r = 0; r < 4; ++r) pk[r] = (short)f2bf(acc[i][j][r] + b);
      *(short4v*)(vT + (size_t)e * (BATCH * SEQ_N) + rbase) = pk;
    }
  }
}

// ---- urc_kernel: {u-gemm (bid<512) | rho (512..2560) | colsumV (2560..3072)} ----
__global__ __launch_bounds__(256)
void urc_kernel(const unsigned short* __restrict__ xb,
                const unsigned short* __restrict__ Bcat2,
                const float* __restrict__ bias2,
                unsigned short* __restrict__ ub,
                const unsigned short* __restrict__ vT,
                const float* __restrict__ wqv,
                const float* __restrict__ bq, const float* __restrict__ bk,
                float* __restrict__ rho, float* __restrict__ colsumV)
{
  __shared__ unsigned short As[128 * 64];
  __shared__ unsigned short Bs[128 * 64];
  const int bid = blockIdx.x, tid = threadIdx.x;
  const int lane = tid & 63, wave = tid >> 6;

  if (bid >= 2560) {
    // ---- colsumV[b][d] = sum_n vT[d][b*4096+n] ----
    const int idx = (bid - 2560) * 4 + wave;   // 0..2047
    const int d = idx >> 1, b = idx & 1;
    const unsigned short* p = vT + (size_t)d * (BATCH * SEQ_N) + b * SEQ_N;
    float s = 0.f;
#pragma unroll
    for (int it = 0; it < 8; ++it) {
      short8 v = *(const short8*)(p + (size_t)(it * 512 + lane * 8));
#pragma unroll
      for (int e = 0; e < 8; ++e) s += bf2f((unsigned short)v[e]);
    }
#pragma unroll
    for (int o = 32; o; o >>= 1) s += __shfl_xor(s, o);
    if (lane == 0) colsumV[b * D_MODEL + d] = s;
    return;
  }

  if (bid >= 512) {
    // ---- rho[i] = xb_i . wqv + bq.bk ----
    const int gi = (bid - 512) * 4 + wave;   // 0..8191
    const unsigned short* xr = xb + (size_t)gi * D_MODEL + lane * 16;
    float s1 = 0.f, s2 = 0.f;
    short8 v0 = *(const short8*)xr, v1 = *(const short8*)(xr + 8);
#pragma unroll
    for (int e = 0; e < 8; ++e) {
      s1 += bf2f((unsigned short)v0[e]) * wqv[lane * 16 + e];
      s1 += bf2f((unsigned short)v1[e]) * wqv[lane * 16 + 8 + e];
    }
#pragma unroll
    for (int e = 0; e < 16; ++e)
      s2 += bq[lane * 16 + e] * bk[lane * 16 + e];
    float s = s1 + s2;
#pragma unroll
    for (int o = 32; o; o >>= 1) s += __shfl_xor(s, o);
    if (lane == 0) rho[gi] = s;
    return;
  }

  // ---- u-gemm: 512 blocks; swapped-operand mfma -> 8B stores to ub ----
  int flat = bid;
  int w    = (flat & 7) * 64 + (flat >> 3);
  int bx = w & 7, by = w >> 3;
  const int bm0 = by * 128;      // x row
  const int bn0 = bx * 128;      // Mt row (u col), 0..1023
  const int wm = (wave >> 1) * 64, wn = (wave & 1) * 64;

  floatx4 acc[4][4] = {};
  for (int k0 = 0; k0 < D_MODEL; k0 += 64) {
#pragma unroll
    for (int t = 0; t < 4; ++t) {
      int bu  = wave * 64 + t * 256;
      int u   = bu + lane;
      int row = u >> 3;
      int c   = (u & 7) ^ (row & 7);
      const unsigned short* srcA = xb + (size_t)(bm0 + row) * D_MODEL + k0 + c * 8;
      __builtin_amdgcn_global_load_lds((const __attribute__((address_space(1))) void*)srcA,
                                       (__attribute__((address_space(3))) void*)(As + bu * 8), 16, 0, 0);
      const unsigned short* srcB = Bcat2 + (size_t)(bn0 + row) * D_MODEL + k0 + c * 8;
      __builtin_amdgcn_global_load_lds((const __attribute__((address_space(1))) void*)srcB,
                                       (__attribute__((address_space(3))) void*)(Bs + bu * 8), 16, 0, 0);
    }
    __syncthreads();
#pragma unroll
    for (int s = 0; s < 2; ++s) {
      short8 af[4], bf[4];
#pragma unroll
      for (int i = 0; i < 4; ++i) {
        int row = wm + i * 16 + (lane & 15);
        int pc  = (s * 4 + (lane >> 4)) ^ (row & 7);
        af[i] = *(const short8*)(As + row * 64 + pc * 8);
      }
#pragma unroll
      for (int j = 0; j < 4; ++j) {
        int row = wn + j * 16 + (lane & 15);
        int pc  = (s * 4 + (lane >> 4)) ^ (row & 7);
        bf[j] = *(const short8*)(Bs + row * 64 + pc * 8);
      }
#pragma unroll
      for (int i = 0; i < 4; ++i)
#pragma unroll
        for (int j = 0; j < 4; ++j)   // swapped: lane&15 <-> x-row, regs <-> col
          acc[i][j] = __builtin_amdgcn_mfma_f32_16x16x32_bf16(bf[j], af[i], acc[i][j], 0, 0, 0);
    }
    __syncthreads();
  }

#pragma unroll
  for (int i = 0; i < 4; ++i) {
#pragma unroll
    for (int j = 0; j < 4; ++j) {
      int xrow = bm0 + wm + i * 16 + (lane & 15);
      int n0   = bn0 + wn + j * 16 + (lane >> 4) * 4;
      floatx4 b4 = *(const floatx4*)(bias2 + n0);
      short4v pk;
#pragma unroll
      for (int r = 0; r < 4; ++r) pk[r] = (short)f2bf(acc[i][j][r] + b4[r]);
      *(short4v*)(ub + (size_t)xrow * D_MODEL + n0) = pk;
    }
  }
}

// ---- lc_kernel: band logits 64x64 tiles (384 blocks); BK=64 + XOR swizzle ----
__global__ __launch_bounds__(256)
void lc_kernel(const unsigned short* __restrict__ U,
               const unsigned short* __restrict__ Xb,
               const float* __restrict__ rho,
               float* __restrict__ Sband,              // [8192][192]
               const float* __restrict__ K1d)
{
  __shared__ unsigned short As[64 * 64];
  __shared__ unsigned short Bs[64 * 64];
  const int bid = blockIdx.x, tid = threadIdx.x;
  const int lane = tid & 63, wave = tid >> 6;

  const int u_  = bid;                   // 0..383
  const int bx  = u_ % 3;                // 64-col tile of the 192 window
  const int gz  = u_ / 3;                // 0..127
  const int g   = gz & 63;
  const int z   = gz >> 6;
  const int bm0 = g * 64;
  const int cb  = g * 64 - 64 + bx * 64; // col base; may be <0 or >=4096
  const int wm = (wave >> 1) * 32, wn = (wave & 1) * 32;

  const unsigned short* Ag = U  + (size_t)z * SEQ_N * D_MODEL;
  const unsigned short* Bg = Xb + (size_t)z * SEQ_N * D_MODEL;

  floatx4 acc[2][2] = {};
  for (int k0 = 0; k0 < D_MODEL; k0 += 64) {
#pragma unroll
    for (int t = 0; t < 2; ++t) {       // A tile [64][64]
      int bu  = wave * 64 + t * 256;
      int u   = bu + lane;
      int row = u >> 3;
      int c   = (u & 7) ^ (row & 7);
      const unsigned short* srcA = Ag + (size_t)(bm0 + row) * D_MODEL + k0 + c * 8;
      __builtin_amdgcn_global_load_lds((const __attribute__((address_space(1))) void*)srcA,
                                       (__attribute__((address_space(3))) void*)(As + bu * 8), 16, 0, 0);
    }
#pragma unroll
    for (int t = 0; t < 2; ++t) {       // B tile [64][64]; rows may be OOB (finite ws, masked in epi)
      int bu  = wave * 64 + t * 256;
      int u   = bu + lane;
      int row = u >> 3;
      int c   = (u & 7) ^ (row & 7);
      const unsigned short* srcB = Bg + (long)(cb + row) * D_MODEL + k0 + c * 8;
      __builtin_amdgcn_global_load_lds((const __attribute__((address_space(1))) void*)srcB,
                                       (__attribute__((address_space(3))) void*)(Bs + bu * 8), 16, 0, 0);
    }
    __syncthreads();
#pragma unroll
    for (int s = 0; s < 2; ++s) {
      short8 af[2], bf[2];
#pragma unroll
      for (int i = 0; i < 2; ++i) {
        int row = wm + i * 16 + (lane & 15);
        int pc  = (s * 4 + (lane >> 4)) ^ (row & 7);
        af[i] = *(const short8*)(As + row * 64 + pc * 8);
      }
#pragma unroll
      for (int j = 0; j < 2; ++j) {
        int row = wn + j * 16 + (lane & 15);
        int pc  = (s * 4 + (lane >> 4)) ^ (row & 7);
        bf[j] = *(const short8*)(Bs + row * 64 + pc * 8);
      }
#pragma unroll
      for (int i = 0; i < 2; ++i)
#pragma unroll
        for (int j = 0; j < 2; ++j)
          acc[i][j] = __builtin_amdgcn_mfma_f32_16x16x32_bf16(af[i], bf[j], acc[i][j], 0, 0, 0);
    }
    __syncthreads();
  }

  float* Cb = Sband + ((size_t)z * SEQ_N + bm0) * BAND + bx * 64;
#pragma unroll
  for (int i = 0; i < 2; ++i) {
    int rl0 = wm + i * 16 + (lane >> 4) * 4;
    float rr[4];
#pragma unroll
    for (int r = 0; r < 4; ++r) rr[r] = rho[(size_t)z * SEQ_N + bm0 + rl0 + r];
#pragma unroll
    for (int j = 0; j < 2; ++j) {
      int cl  = wn + j * 16 + (lane & 15);
#pragma unroll
      for (int r = 0; r < 4; ++r) {
        int col = cb + cl;
        int d = (bm0 + rl0 + r) - col; d = d < 0 ? -d : d;   // <= 127
        float v = ((unsigned)col < (unsigned)SEQ_N)
                    ? (acc[i][j][r] + rr[r]) * 0.03125f * K1d[d] : 0.f;
        Cb[(size_t)(rl0 + r) * BAND + cl] = v;
      }
    }
  }
}

// ---- sk_kernel: {band softmax (bid<2048) | writeK} fused (18432 blocks) ----
__global__ __launch_bounds__(256)
void sk_kernel(const float* __restrict__ Sband,
               float* __restrict__ attn,
               unsigned short* __restrict__ Pb,
               float* __restrict__ c_arr,
               float* __restrict__ Kout,
               const float* __restrict__ K1d)
{
  __shared__ float lds_e[4][BAND];
  const int bid = blockIdx.x, tid = threadIdx.x;
  const int lane = tid & 63, wave = tid >> 6;

  if (bid >= 2048) {
    // ---- writeK: K[i,j] = K1d[|i-j|] ----
    size_t t = (size_t)(bid - 2048) * 256 + tid;
    size_t f = t * 4;
    int i = (int)(f >> 12);
    int j = (int)(f & 4095);
    floatx4 v;
#pragma unroll
    for (int e = 0; e < 4; ++e) {
      int d = i - (j + e); d = d < 0 ? -d : d;
      v[e] = K1d[d];
    }
    __builtin_nontemporal_store(v, (floatx4*)(Kout + f));
    return;
  }

  const int gi = bid * 4 + wave;     // 0..8191
  const int ii = gi & (SEQ_N - 1);
  const int g  = ii >> 6;
  const int cbase = g * 64 - 64;
  const float* S = Sband + (size_t)gi * BAND;

  float sv[3];
  float m = 0.0f;                           // far logits are exactly 0
#pragma unroll
  for (int j = 0; j < 3; ++j) {
    int t = j * 64 + lane;
    int col = cbase + t;
    sv[j] = S[t];
    if ((unsigned)col < (unsigned)SEQ_N) m = fmaxf(m, sv[j]);
  }
#pragma unroll
  for (int o = 32; o; o >>= 1) m = fmaxf(m, __shfl_xor(m, o));

  float s = 0.f;
#pragma unroll
  for (int j = 0; j < 3; ++j) {
    int t = j * 64 + lane;
    int col = cbase + t;
    float e = ((unsigned)col < (unsigned)SEQ_N) ? __expf(sv[j] - m) : 0.f;
    sv[j] = e;
    s += e;
  }
#pragma unroll
  for (int o = 32; o; o >>= 1) s += __shfl_xor(s, o);

  int n_valid = BAND - ((g == 0) ? 64 : 0) - ((g == 63) ? 64 : 0);
  float efar  = __expf(-m);
  float denom = s + (float)(SEQ_N - n_valid) * efar;
  float inv   = 1.0f / denom;
  float c     = efar * inv;

  unsigned short* prow = Pb + (size_t)gi * BAND;
#pragma unroll
  for (int j = 0; j < 3; ++j) {
    int t = j * 64 + lane;
    float p = sv[j] * inv;
    lds_e[wave][t] = p;
    int col = cbase + t;
    prow[t] = ((unsigned)col < (unsigned)SEQ_N) ? f2bf(p - c) : (unsigned short)0;
  }
  if (lane == 0) c_arr[gi] = c;

  float* arow = attn + (size_t)gi * SEQ_N;
#pragma unroll
  for (int jj = 0; jj < 16; ++jj) {
    int col0 = jj * 256 + lane * 4;
    floatx4 o;
#pragma unroll
    for (int e = 0; e < 4; ++e) {
      int t = col0 + e - cbase;
      o[e] = ((unsigned)t < (unsigned)BAND) ? lds_e[wave][t] : c;
    }
    __builtin_nontemporal_store(o, (floatx4*)(arow + col0));
  }
}

// ---- band PV: out = (P-c) @ V_band + c * colsumV; K=192, BK=64 + XOR swizzle ----
__global__ __launch_bounds__(256)
void band_pv(const unsigned short* __restrict__ Pb,   // [8192][192]
             const unsigned short* __restrict__ vT,   // [1024][8192]
             const float* __restrict__ c_arr,         // [8192]
             const float* __restrict__ colsumV,       // [2][1024]
             float* __restrict__ outp)                // [2][4096][1024]
{
  __shared__ unsigned short As[64 * 64];
  __shared__ unsigned short Bs[128 * 64];
  const int tid = threadIdx.x, lane = tid & 63, wave = tid >> 6;
  const int bx = blockIdx.x;     // 0..7  d-block (128 cols)
  const int g  = blockIdx.y;     // 0..63 64-row group
  const int z  = blockIdx.z;
  const int bm0 = g * 64;
  const int bn0 = bx * 128;
  const int wm = (wave >> 1) * 32, wn = (wave & 1) * 64;

  const unsigned short* Ag = Pb + ((size_t)z * SEQ_N + bm0) * BAND;
  // B row d, band col t -> vT[d][z*4096 + g*64 - 64 + t]; +-64 overrun lands in
  // adjacent ws buffers (finite bf16, always multiplied by P==0).
  const unsigned short* Bg = vT + (long)z * SEQ_N + (long)bm0 - 64;

  floatx4 acc[2][4] = {};
  for (int k0 = 0; k0 < BAND; k0 += 64) {
#pragma unroll
    for (int t = 0; t < 2; ++t) {
      int bu  = wave * 64 + t * 256;
      int u   = bu + lane;
      int row = u >> 3;
      int c   = (u & 7) ^ (row & 7);
      const unsigned short* srcA = Ag + (size_t)row * BAND + k0 + c * 8;
      __builtin_amdgcn_global_load_lds((const __attribute__((address_space(1))) void*)srcA,
                                       (__attribute__((address_space(3))) void*)(As + bu * 8), 16, 0, 0);
    }
#pragma unroll
    for (int t = 0; t < 4; ++t) {
      int bu  = wave * 64 + t * 256;
      int u   = bu + lane;
      int row = u >> 3;
      int c   = (u & 7) ^ (row & 7);
      const unsigned short* srcB = Bg + (size_t)(bn0 + row) * (BATCH * SEQ_N) + k0 + c * 8;
      __builtin_amdgcn_global_load_lds((const __attribute__((address_space(1))) void*)srcB,
                                       (__attribute__((address_space(3))) void*)(Bs + bu * 8), 16, 0, 0);
    }
    __syncthreads();
#pragma unroll
    for (int s = 0; s < 2; ++s) {
      short8 af[2], bf[4];
#pragma unroll
      for (int i = 0; i < 2; ++i) {
        int row = wm + i * 16 + (lane & 15);
        int pc  = (s * 4 + (lane >> 4)) ^ (row & 7);
        af[i] = *(const short8*)(As + row * 64 + pc * 8);
      }
#pragma unroll
      for (int j = 0; j < 4; ++j) {
        int row = wn + j * 16 + (lane & 15);
        int pc  = (s * 4 + (lane >> 4)) ^ (row & 7);
        bf[j] = *(const short8*)(Bs + row * 64 + pc * 8);
      }
#pragma unroll
      for (int i = 0; i < 2; ++i)
#pragma unroll
        for (int j = 0; j < 4; ++j)
          acc[i][j] = __builtin_amdgcn_mfma_f32_16x16x32_bf16(af[i], bf[j], acc[i][j], 0, 0, 0);
    }
    __syncthreads();
  }

#pragma unroll
  for (int i = 0; i < 2; ++i) {
#pragma unroll
    for (int j = 0; j < 4; ++j) {
      int col   = bn0 + wn + j * 16 + (lane & 15);
      int rbase = bm0 + wm + i * 16 + (lane >> 4) * 4;
      float csv = colsumV[z * D_MODEL + col];
#pragma unroll
      for (int r = 0; r < 4; ++r) {
        int row = rbase + r;
        float o = acc[i][j][r] + c_arr[(size_t)z * SEQ_N + row] * csv;
        __builtin_nontemporal_store(o, outp + ((size_t)z * SEQ_N + row) * D_MODEL + col);
      }
    }
  }
}

// ---------------- fallback-path kernels (round-1 proven) ----------------
__global__ void k1d_kernel(float* __restrict__ K1d,
                           const float* __restrict__ alpha_p,
                           const float* __restrict__ lam_p) {
  int r = blockIdx.x * blockDim.x + threadIdx.x;
  if (r >= SEQ_N) return;
  float a   = fabsf(alpha_p[0]);
  float lam = fabsf(lam_p[0]);
  float rf  = (float)r;
  K1d[r] = powf(rf + 1e-4f, -a) * expf(-rf / lam);
}

__global__ __launch_bounds__(256) void writeK_kernel(float* __restrict__ Kout,
                                                     const float* __restrict__ K1d) {
  size_t t = (size_t)blockIdx.x * 256 + threadIdx.x;
  size_t f = t * 4;
  int i = (int)(f >> 12);
  int j = (int)(f & 4095);
  floatx4 v;
#pragma unroll
  for (int e = 0; e < 4; ++e) {
    int d = i - (j + e); d = d < 0 ? -d : d;
    v[e] = K1d[d];
  }
  __builtin_nontemporal_store(v, (floatx4*)(Kout + f));
}

#define BM 128
#define BN 128
#define BK 32

template<int ASRC, int BSRC, int EPI>
__global__ __launch_bounds__(256)
void gemm_bt(const void* __restrict__ Ap_, int lda, long sA,
             const void* __restrict__ Bp_, int ldb, long sB,
             void* __restrict__ Cp_, int ldc, long sC,
             int K, const float* __restrict__ bias,
             const float* __restrict__ K1d)
{
  __shared__ unsigned short As[BM * BK];
  __shared__ unsigned short Bs[BN * BK];
  const int tid  = threadIdx.x;
  const int lane = tid & 63;
  const int wave = tid >> 6;

  int gx = (int)gridDim.x, gy = (int)gridDim.y;
  int total = gx * gy * (int)gridDim.z;
  int flat  = (int)blockIdx.z * gx * gy + (int)blockIdx.y * gx + (int)blockIdx.x;
  int w     = (flat & 7) * (total >> 3) + (flat >> 3);
  int bx = w % gx;
  int t_ = w / gx;
  int by = t_ % gy;
  int z  = t_ / gy;

  const int bm0  = by * BM;
  const int bn0  = bx * BN;
  const int wm   = (wave >> 1) * 64;
  const int wn   = (wave & 1) * 64;

  floatx4 acc[4][4] = {};

  const unsigned short* Agb = (const unsigned short*)Ap_ + (size_t)z * (size_t)sA;
  const float*          Agf = (const float*)Ap_          + (size_t)z * (size_t)sA;
  const unsigned short* Bgb = (const unsigned short*)Bp_ + (size_t)z * (size_t)sB;
  const float*          Bgf = (const float*)Bp_          + (size_t)z * (size_t)sB;

  for (int k0 = 0; k0 < K; k0 += BK) {
    if constexpr (ASRC == 0) {
#pragma unroll
      for (int t = 0; t < 2; ++t) {
        int bu = wave * 64 + t * 256;
        int u  = bu + lane;
        const unsigned short* src = Agb + (size_t)(bm0 + (u >> 2)) * lda + k0 + (u & 3) * 8;
        __builtin_amdgcn_global_load_lds((const __attribute__((address_space(1))) void*)src,
                                         (__attribute__((address_space(3))) void*)(As + bu * 8),
                                         16, 0, 0);
      }
    } else {
#pragma unroll
      for (int t = 0; t < 2; ++t) {
        int u = tid + t * 256;
        const float* src = Agf + (size_t)(bm0 + (u >> 2)) * lda + k0 + (u & 3) * 8;
        floatx4 x0 = *(const floatx4*)src;
        floatx4 x1 = *(const floatx4*)(src + 4);
        short8 pk;
        pk[0] = (short)f2bf(x0[0]); pk[1] = (short)f2bf(x0[1]);
        pk[2] = (short)f2bf(x0[2]); pk[3] = (short)f2bf(x0[3]);
        pk[4] = (short)f2bf(x1[0]); pk[5] = (short)f2bf(x1[1]);
        pk[6] = (short)f2bf(x1[2]); pk[7] = (short)f2bf(x1[3]);
        *(short8*)(As + u * 8) = pk;
      }
    }
    if constexpr (BSRC == 0) {
#pragma unroll
      for (int t = 0; t < 2; ++t) {
        int bu = wave * 64 + t * 256;
        int u  = bu + lane;
        const unsigned short* src = Bgb + (size_t)(bn0 + (u >> 2)) * ldb + k0 + (u & 3) * 8;
        __builtin_amdgcn_global_load_lds((const __attribute__((address_space(1))) void*)src,
                                         (__attribute__((address_space(3))) void*)(Bs + bu * 8),
                                         16, 0, 0);
      }
    } else {
#pragma unroll
      for (int t = 0; t < 2; ++t) {
        int u = tid + t * 256;
        const float* src = Bgf + (size_t)(bn0 + (u >> 2)) * ldb + k0 + (u & 3) * 8;
        floatx4 x0 = *(const floatx4*)src;
        floatx4 x1 = *(const floatx4*)(src + 4);
        short8 pk;
        pk[0] = (short)f2bf(x0[0]); pk[1] = (short)f2bf(x0[1]);
        pk[2] = (short)f2bf(x0[2]); pk[3] = (short)f2bf(x0[3]);
        pk[4] = (short)f2bf(x1[0]); pk[5] = (short)f2bf(x1[1]);
        pk[6] = (short)f2bf(x1[2]); pk[7] = (short)f2bf(x1[3]);
        *(short8*)(Bs + u * 8) = pk;
      }
    }
    __syncthreads();

    short8 af[4], bf[4];
#pragma unroll
    for (int i = 0; i < 4; ++i)
      af[i] = *(const short8*)(As + (wm + i * 16 + (lane & 15)) * BK + (lane >> 4) * 8);
#pragma unroll
    for (int j = 0; j < 4; ++j)
      bf[j] = *(const short8*)(Bs + (wn + j * 16 + (lane & 15)) * BK + (lane >> 4) * 8);
#pragma unroll
    for (int i = 0; i < 4; ++i)
#pragma unroll
      for (int j = 0; j < 4; ++j)
        acc[i][j] = __builtin_amdgcn_mfma_f32_16x16x32_bf16(af[i], bf[j], acc[i][j], 0, 0, 0);
    __syncthreads();
  }

  const int col0 = bn0 + wn;
  const int row0 = bm0 + wm;
#pragma unroll
  for (int i = 0; i < 4; ++i) {
#pragma unroll
    for (int j = 0; j < 4; ++j) {
      int col   = col0 + j * 16 + (lane & 15);
      int rbase = row0 + i * 16 + (lane >> 4) * 4;
      if constexpr (EPI == 0) {
        unsigned short* C = (unsigned short*)Cp_ + (size_t)z * (size_t)sC;
        float b = bias[col];
#pragma unroll
        for (int r = 0; r < 4; ++r)
          C[(size_t)(rbase + r) * ldc + col] = f2bf(acc[i][j][r] + b);
      } else if constexpr (EPI == 1) {
        unsigned short* C = (unsigned short*)Cp_ + (size_t)z * (size_t)sC;
#pragma unroll
        for (int r = 0; r < 4; ++r)
          C[(size_t)(rbase + r) * ldc + col] = f2bf(acc[i][j][r] + bias[rbase + r]);
      } else if constexpr (EPI == 2) {
        float* C = (float*)Cp_ + (size_t)z * (size_t)sC;
#pragma unroll
        for (int r = 0; r < 4; ++r) {
          int row = rbase + r;
          int d = row - col; d = d < 0 ? -d : d;
          C[(size_t)row * ldc + col] = acc[i][j][r] * 0.03125f * K1d[d];
        }
      } else {
        float* C = (float*)Cp_ + (size_t)z * (size_t)sC;
#pragma unroll
        for (int r = 0; r < 4; ++r)
          C[(size_t)(rbase + r) * ldc + col] = acc[i][j][r];
      }
    }
  }
}

__global__ __launch_bounds__(256)
void softmax_kernel(float* __restrict__ attn) {
  const int tid = threadIdx.x;
  float* p = attn + (size_t)blockIdx.x * SEQ_N;
  floatx4* p4 = (floatx4*)p;
  floatx4 x[4];
  float m = -3.402823466e+38f;
#pragma unroll
  for (int c = 0; c < 4; ++c) {
    x[c] = p4[tid + c * 256];
    m = fmaxf(m, fmaxf(fmaxf(x[c][0], x[c][1]), fmaxf(x[c][2], x[c][3])));
  }
#pragma unroll
  for (int o = 32; o; o >>= 1) m = fmaxf(m, __shfl_xor(m, o));
  __shared__ float redm[4], reds[4];
  if ((tid & 63) == 0) redm[tid >> 6] = m;
  __syncthreads();
  m = fmaxf(fmaxf(redm[0], redm[1]), fmaxf(redm[2], redm[3]));
  float s = 0.f;
#pragma unroll
  for (int c = 0; c < 4; ++c)
#pragma unroll
    for (int e = 0; e < 4; ++e) {
      float t = __expf(x[c][e] - m);
      x[c][e] = t;
      s += t;
    }
#pragma unroll
  for (int o = 32; o; o >>= 1) s += __shfl_xor(s, o);
  if ((tid & 63) == 0) reds[tid >> 6] = s;
  __syncthreads();
  s = reds[0] + reds[1] + reds[2] + reds[3];
  float inv = 1.0f / s;
#pragma unroll
  for (int c = 0; c < 4; ++c) {
    floatx4 y;
#pragma unroll
    for (int e = 0; e < 4; ++e) y[e] = x[c][e] * inv;
    p4[tid + c * 256] = y;
  }
}

extern "C" void kernel_launch(void* const* d_in, const int* in_sizes, int n_in,
                              void* d_out, int out_size, void* d_ws, size_t ws_size,
                              hipStream_t stream) {
  const float* x     = (const float*)d_in[0];
  const float* Wq    = (const float*)d_in[1];
  const float* bq    = (const float*)d_in[2];
  const float* Wk    = (const float*)d_in[3];
  const float* bk    = (const float*)d_in[4];
  const float* Wv    = (const float*)d_in[5];
  const float* bv    = (const float*)d_in[6];
  const float* alpha = (const float*)d_in[7];
  const float* lam   = (const float*)d_in[8];

  float* outp  = (float*)d_out;
  float* attnp = outp + (size_t)BATCH * SEQ_N * D_MODEL;
  float* Kp    = attnp + (size_t)BATCH * SEQ_N * SEQ_N;

  char* ws = (char*)d_ws;
  float* K1d = (float*)ws;                                  // 16 KB
  unsigned short* vT   = (unsigned short*)(ws + 16384);     // [1024][8192]
  unsigned short* xb   = vT + NELEM;                        // [8192][1024]
  unsigned short* ub   = xb + NELEM;                        // [8192][1024]  u' bf16
  unsigned short* wqT  = ub + NELEM;                        // [1024][1024]
  unsigned short* wkT  = wqT + (size_t)D_MODEL * D_MODEL;   // [1024][1024]
  unsigned short* Bcat2 = wkT + (size_t)D_MODEL * D_MODEL;  // [2048][1024]: Mt | Wv
  float* Sband   = (float*)(Bcat2 + (size_t)2 * D_MODEL * D_MODEL); // [8192][192]
  unsigned short* Pb = (unsigned short*)(Sband + (size_t)BATCH * SEQ_N * BAND);
  float* c_arr   = (float*)(Pb + (size_t)BATCH * SEQ_N * BAND);     // [8192]
  float* colsumV = c_arr + (size_t)BATCH * SEQ_N;                   // [2][1024]
  float* bias2   = colsumV + (size_t)BATCH * D_MODEL;               // [2048]
  float* wqv     = bias2 + 2 * D_MODEL;                             // [1024]
  float* rho     = wqv + D_MODEL;                                   // [8192]

  size_t need = (size_t)((char*)(rho + BATCH * SEQ_N) - ws);
  const bool fast = ws_size >= need;

  if (fast) {
    fused_prep<<<5140, 256, 0, stream>>>(x, Wq, Wk, Wv, bv, alpha, lam,
                                         xb, Bcat2, wqT, wkT, bias2, K1d);
    vwm_kernel<<<1280, 256, 0, stream>>>(xb, Bcat2, vT, wkT, wqT, bq, bk,
                                         Bcat2, bias2, wqv);
    urc_kernel<<<3072, 256, 0, stream>>>(xb, Bcat2, bias2, ub, vT, wqv, bq, bk,
                                         rho, colsumV);
    lc_kernel<<<384, 256, 0, stream>>>(ub, xb, rho, Sband, K1d);
    sk_kernel<<<18432, 256, 0, stream>>>(Sband, attnp, Pb, c_arr, Kp, K1d);
    band_pv<<<dim3(D_MODEL / 128, SEQ_N / 64, BATCH), 256, 0, stream>>>(
        Pb, vT, c_arr, colsumV, outp);
  } else {
    // fallback: round-1 proven path (qb->xb slot, kb->ub slot)
    unsigned short* qb = xb;
    unsigned short* kb = ub;
    k1d_kernel<<<16, 256, 0, stream>>>(K1d, alpha, lam);
    writeK_kernel<<<(SEQ_N * SEQ_N / 4) / 256, 256, 0, stream>>>(Kp, K1d);
    gemm_bt<1, 1, 0><<<dim3(D_MODEL / BN, BATCH * SEQ_N / BM, 1), 256, 0, stream>>>(
        x, D_MODEL, 0, Wq, D_MODEL, 0, qb, D_MODEL, 0, D_MODEL, bq, nullptr);
    gemm_bt<1, 1, 0><<<dim3(D_MODEL / BN, BATCH * SEQ_N / BM, 1), 256, 0, stream>>>(
        x, D_MODEL, 0, Wk, D_MODEL, 0, kb, D_MODEL, 0, D_MODEL, bk, nullptr);
    gemm_bt<1, 1, 1><<<dim3(BATCH * SEQ_N / BN, D_MODEL / BM, 1), 256, 0, stream>>>(
        Wv, D_MODEL, 0, x, D_MODEL, 0, vT, BATCH * SEQ_N, 0, D_MODEL, bv, nullptr);
    gemm_bt<0, 0, 2><<<dim3(SEQ_N / BN, SEQ_N / BM, BATCH), 256, 0, stream>>>(
        qb, D_MODEL, (long)SEQ_N * D_MODEL, kb, D_MODEL, (long)SEQ_N * D_MODEL,
        attnp, SEQ_N, (long)SEQ_N * SEQ_N, D_MODEL, nullptr, K1d);
    softmax_kernel<<<BATCH * SEQ_N, 256, 0, stream>>>(attnp);
    gemm_bt<1, 0, 3><<<dim3(D_MODEL / BN, SEQ_N / BM, BATCH), 256, 0, stream>>>(
        attnp, SEQ_N, (long)SEQ_N * SEQ_N, vT, BATCH * SEQ_N, (long)SEQ_N,
        outp, D_MODEL, (long)SEQ_N * D_MODEL, SEQ_N, nullptr, nullptr);
  }
}

// Round 18
// 156.556 us; speedup vs baseline: 1.0203x; 1.0203x over previous
//
#include <hip/hip_runtime.h>
#include <hip/hip_bf16.h>
#include <cstdint>
#include <cstddef>

#define D_MODEL 1024
#define SEQ_N   4096
#define BATCH   2
#define BAND    192   // 3 x 64-col window [g*64-64, g*64+128) per 64-row group g (+-64 coverage)
#define NELEM   ((size_t)BATCH * SEQ_N * D_MODEL)   // 8388608

typedef __attribute__((ext_vector_type(4))) float  floatx4;
typedef __attribute__((ext_vector_type(8))) short  short8;
typedef __attribute__((ext_vector_type(4))) short  short4v;

__device__ __forceinline__ unsigned short f2bf(float f) {
  unsigned u = __float_as_uint(f);
  u += 0x7FFFu + ((u >> 16) & 1u);   // round-to-nearest-even
  return (unsigned short)(u >> 16);
}
__device__ __forceinline__ float bf2f(unsigned short u) {
  return __uint_as_float(((unsigned)u) << 16);
}

// ---- fused prep: x->xb, Wv->Bcat2 hi (bf16), Wq/Wk -> transposed bf16, K1d, bv bias ----
__global__ __launch_bounds__(256)
void fused_prep(const float* __restrict__ x,
                const float* __restrict__ Wq, const float* __restrict__ Wk,
                const float* __restrict__ Wv, const float* __restrict__ bv,
                const float* __restrict__ alpha_p, const float* __restrict__ lam_p,
                unsigned short* __restrict__ xb,
                unsigned short* __restrict__ Bcat2,   // [2048][1024]; rows 1024.. = Wv bf16
                unsigned short* __restrict__ wqT,     // [1024][1024] = Wq^T bf16
                unsigned short* __restrict__ wkT,     // [1024][1024] = Wk^T bf16
                float* __restrict__ bias2,            // [2048]; hi half = bv
                float* __restrict__ K1d)
{
  __shared__ unsigned short Tld[64][66];
  int bid = blockIdx.x, tid = threadIdx.x;
  if (bid < 4096) {                       // x -> xb
    int i = bid * 256 + tid;
    const floatx4* s4 = (const floatx4*)x;
    floatx4 a = s4[i * 2], b = s4[i * 2 + 1];
    short8 pk;
    pk[0] = (short)f2bf(a[0]); pk[1] = (short)f2bf(a[1]);
    pk[2] = (short)f2bf(a[2]); pk[3] = (short)f2bf(a[3]);
    pk[4] = (short)f2bf(b[0]); pk[5] = (short)f2bf(b[1]);
    pk[6] = (short)f2bf(b[2]); pk[7] = (short)f2bf(b[3]);
    *(short8*)(xb + (size_t)i * 8) = pk;
  } else if (bid < 4608) {                // Wv -> Bcat2 rows 1024..2047
    int i = (bid - 4096) * 256 + tid;     // < 131072
    const floatx4* s4 = (const floatx4*)Wv;
    floatx4 a = s4[i * 2], b = s4[i * 2 + 1];
    short8 pk;
    pk[0] = (short)f2bf(a[0]); pk[1] = (short)f2bf(a[1]);
    pk[2] = (short)f2bf(a[2]); pk[3] = (short)f2bf(a[3]);
    pk[4] = (short)f2bf(b[0]); pk[5] = (short)f2bf(b[1]);
    pk[6] = (short)f2bf(b[2]); pk[7] = (short)f2bf(b[3]);
    *(short8*)(Bcat2 + (size_t)D_MODEL * D_MODEL + (size_t)i * 8) = pk;
  } else if (bid < 5120) {                // transpose Wq / Wk -> bf16
    int u = bid - 4608;                   // 0..511
    const float* src = (u < 256) ? Wq : Wk;
    unsigned short* dst = (u < 256) ? wqT : wkT;
    int t = u & 255;
    int tr = t >> 4, tc = t & 15;         // 64x64 tile (tr,tc)
    int rl = tid >> 2, cc = (tid & 3) * 16;
    const float* sp = src + (size_t)(tr * 64 + rl) * D_MODEL + tc * 64 + cc;
#pragma unroll
    for (int q4 = 0; q4 < 4; ++q4) {
      floatx4 v = *(const floatx4*)(sp + q4 * 4);
#pragma unroll
      for (int e = 0; e < 4; ++e) Tld[cc + q4 * 4 + e][rl] = f2bf(v[e]);
    }
    __syncthreads();
    int cl = tid >> 2, rchunk = (tid & 3) * 16;
    short8 o0, o1;
#pragma unroll
    for (int e = 0; e < 8; ++e) { o0[e] = (short)Tld[cl][rchunk + e]; o1[e] = (short)Tld[cl][rchunk + 8 + e]; }
    unsigned short* dp = dst + (size_t)(tc * 64 + cl) * D_MODEL + tr * 64 + rchunk;
    *(short8*)dp = o0;
    *(short8*)(dp + 8) = o1;
  } else {                                // K1d + bv bias
    int t = (bid - 5120) * 256 + tid;     // 0..5119
    if (t < SEQ_N) {
      float a   = fabsf(alpha_p[0]);
      float lam = fabsf(lam_p[0]);
      float rf  = (float)t;
      K1d[t] = powf(rf + 1e-4f, -a) * expf(-rf / lam);
    }
    int v = t - SEQ_N;
    if (v >= 0 && v < D_MODEL) bias2[D_MODEL + v] = bv[v];
  }
}

// ---- wg_kernel: {wtilde | Mt gemm} fused (768 blocks) ----
__global__ __launch_bounds__(256)
void wg_kernel(const unsigned short* __restrict__ wkT,
               const unsigned short* __restrict__ wqT,
               const float* __restrict__ bq, const float* __restrict__ bk,
               unsigned short* __restrict__ Mt,        // = Bcat2 rows 0..1023
               float* __restrict__ bias2, float* __restrict__ wqv)
{
  __shared__ unsigned short As[64 * 32];
  __shared__ unsigned short Bs[64 * 32];
  const int bid = blockIdx.x, tid = threadIdx.x;
  const int lane = tid & 63, wave = tid >> 6;

  if (bid < 512) {
    // ---- wtilde ----
    const int idx = bid * 4 + wave;           // 0..2047
    const int d = idx & (D_MODEL - 1);
    const bool isK = idx < D_MODEL;
    const unsigned short* row = (isK ? wkT : wqT) + (size_t)d * D_MODEL + lane * 16;
    const float* b = isK ? bq : bk;
    float s = 0.f;
    short8 v0 = *(const short8*)row, v1 = *(const short8*)(row + 8);
#pragma unroll
    for (int e = 0; e < 8; ++e) {
      s += bf2f((unsigned short)v0[e]) * b[lane * 16 + e];
      s += bf2f((unsigned short)v1[e]) * b[lane * 16 + 8 + e];
    }
#pragma unroll
    for (int o = 32; o; o >>= 1) s += __shfl_xor(s, o);
    if (lane == 0) { if (isK) bias2[d] = s; else wqv[d] = s; }
    return;
  }

  // ---- Mt = wkT (bt) wqT, 64x64 tiles ----
  int flat = bid - 512;                       // 0..255
  int w = (flat & 7) * 32 + (flat >> 3);
  int bx = w % 16, by = w / 16;
  const int bm0 = by * 64, bn0 = bx * 64;
  const int wm = (wave >> 1) * 32, wn = (wave & 1) * 32;

  floatx4 acc[2][2] = {};
  for (int k0 = 0; k0 < D_MODEL; k0 += 32) {
    {
      int bu = wave * 64;
      int u  = bu + lane;
      const unsigned short* srcA = wkT + (size_t)(bm0 + (u >> 2)) * D_MODEL + k0 + (u & 3) * 8;
      __builtin_amdgcn_global_load_lds((const __attribute__((address_space(1))) void*)srcA,
                                       (__attribute__((address_space(3))) void*)(As + bu * 8), 16, 0, 0);
      const unsigned short* srcB = wqT + (size_t)(bn0 + (u >> 2)) * D_MODEL + k0 + (u & 3) * 8;
      __builtin_amdgcn_global_load_lds((const __attribute__((address_space(1))) void*)srcB,
                                       (__attribute__((address_space(3))) void*)(Bs + bu * 8), 16, 0, 0);
    }
    __syncthreads();
    short8 af[2], bf[2];
#pragma unroll
    for (int i = 0; i < 2; ++i)
      af[i] = *(const short8*)(As + (wm + i * 16 + (lane & 15)) * 32 + (lane >> 4) * 8);
#pragma unroll
    for (int j = 0; j < 2; ++j)
      bf[j] = *(const short8*)(Bs + (wn + j * 16 + (lane & 15)) * 32 + (lane >> 4) * 8);
#pragma unroll
    for (int i = 0; i < 2; ++i)
#pragma unroll
      for (int j = 0; j < 2; ++j)
        acc[i][j] = __builtin_amdgcn_mfma_f32_16x16x32_bf16(af[i], bf[j], acc[i][j], 0, 0, 0);
    __syncthreads();
  }
#pragma unroll
  for (int i = 0; i < 2; ++i) {
#pragma unroll
    for (int j = 0; j < 2; ++j) {
      int col   = bn0 + wn + j * 16 + (lane & 15);
      int rbase = bm0 + wm + i * 16 + (lane >> 4) * 4;
#pragma unroll
      for (int r = 0; r < 4; ++r)
        Mt[(size_t)(rbase + r) * D_MODEL + col] = f2bf(acc[i][j][r]);
    }
  }
}

// ---- uvr_kernel: {uv gemm (bid<1024) | rho (bid>=1024)} fused (3072 blocks) ----
__global__ __launch_bounds__(256)
void uvr_kernel(const unsigned short* __restrict__ xb,
                const unsigned short* __restrict__ Bcat2,
                const float* __restrict__ bias2,
                unsigned short* __restrict__ ub,
                unsigned short* __restrict__ vT,
                const float* __restrict__ wqv,
                const float* __restrict__ bq, const float* __restrict__ bk,
                float* __restrict__ rho)
{
  __shared__ unsigned short As[128 * 64];
  __shared__ unsigned short Bs[128 * 64];
  const int bid = blockIdx.x, tid = threadIdx.x;
  const int lane = tid & 63, wave = tid >> 6;

  if (bid >= 1024) {
    // ---- rho ----
    const int gi = (bid - 1024) * 4 + wave;   // 0..8191
    const unsigned short* xr = xb + (size_t)gi * D_MODEL + lane * 16;
    float s1 = 0.f, s2 = 0.f;
    short8 v0 = *(const short8*)xr, v1 = *(const short8*)(xr + 8);
#pragma unroll
    for (int e = 0; e < 8; ++e) {
      s1 += bf2f((unsigned short)v0[e]) * wqv[lane * 16 + e];
      s1 += bf2f((unsigned short)v1[e]) * wqv[lane * 16 + 8 + e];
    }
#pragma unroll
    for (int e = 0; e < 16; ++e)
      s2 += bq[lane * 16 + e] * bk[lane * 16 + e];
    float s = s1 + s2;
#pragma unroll
    for (int o = 32; o; o >>= 1) s += __shfl_xor(s, o);
    if (lane == 0) rho[gi] = s;
    return;
  }

  // ---- uv gemm; XCD swizzle over total=1024 ----
  int flat  = bid;
  int w     = (flat & 7) * 128 + (flat >> 3);
  int bx = w % 16, by = w / 16;
  const int bm0 = by * 128;      // x row
  const int bn0 = bx * 128;      // col in 2048
  const int wm = (wave >> 1) * 64, wn = (wave & 1) * 64;
  const bool isU = (bn0 < D_MODEL);

  floatx4 acc[4][4] = {};
  for (int k0 = 0; k0 < D_MODEL; k0 += 64) {
#pragma unroll
    for (int t = 0; t < 4; ++t) {
      int bu  = wave * 64 + t * 256;       // wave-uniform unit base
      int u   = bu + lane;                 // unit: row=u>>3, phys chunk=u&7
      int row = u >> 3;
      int c   = (u & 7) ^ (row & 7);       // logical chunk belonging at this phys slot
      const unsigned short* srcA = xb + (size_t)(bm0 + row) * D_MODEL + k0 + c * 8;
      __builtin_amdgcn_global_load_lds((const __attribute__((address_space(1))) void*)srcA,
                                       (__attribute__((address_space(3))) void*)(As + bu * 8), 16, 0, 0);
      const unsigned short* srcB = Bcat2 + (size_t)(bn0 + row) * D_MODEL + k0 + c * 8;
      __builtin_amdgcn_global_load_lds((const __attribute__((address_space(1))) void*)srcB,
                                       (__attribute__((address_space(3))) void*)(Bs + bu * 8), 16, 0, 0);
    }
    __syncthreads();
#pragma unroll
    for (int s = 0; s < 2; ++s) {
      short8 af[4], bf[4];
#pragma unroll
      for (int i = 0; i < 4; ++i) {
        int row = wm + i * 16 + (lane & 15);
        int pc  = (s * 4 + (lane >> 4)) ^ (row & 7);
        af[i] = *(const short8*)(As + row * 64 + pc * 8);
      }
#pragma unroll
      for (int j = 0; j < 4; ++j) {
        int row = wn + j * 16 + (lane & 15);
        int pc  = (s * 4 + (lane >> 4)) ^ (row & 7);
        bf[j] = *(const short8*)(Bs + row * 64 + pc * 8);
      }
      if (isU) {
#pragma unroll
        for (int i = 0; i < 4; ++i)
#pragma unroll
          for (int j = 0; j < 4; ++j)   // swapped: lane&15 <-> x-row, regs <-> col
            acc[i][j] = __builtin_amdgcn_mfma_f32_16x16x32_bf16(bf[j], af[i], acc[i][j], 0, 0, 0);
      } else {
#pragma unroll
        for (int i = 0; i < 4; ++i)
#pragma unroll
          for (int j = 0; j < 4; ++j)
            acc[i][j] = __builtin_amdgcn_mfma_f32_16x16x32_bf16(af[i], bf[j], acc[i][j], 0, 0, 0);
      }
    }
    __syncthreads();
  }

  if (isU) {
#pragma unroll
    for (int i = 0; i < 4; ++i) {
#pragma unroll
      for (int j = 0; j < 4; ++j) {
        int xrow = bm0 + wm + i * 16 + (lane & 15);
        int n0   = bn0 + wn + j * 16 + (lane >> 4) * 4;
        floatx4 b4 = *(const floatx4*)(bias2 + n0);
        short4v pk;
#pragma unroll
        for (int r = 0; r < 4; ++r) pk[r] = (short)f2bf(acc[i][j][r] + b4[r]);
        *(short4v*)(ub + (size_t)xrow * D_MODEL + n0) = pk;
      }
    }
  } else {
#pragma unroll
    for (int i = 0; i < 4; ++i) {
#pragma unroll
      for (int j = 0; j < 4; ++j) {
        int n     = bn0 + wn + j * 16 + (lane & 15);
        int e     = n - D_MODEL;
        int rbase = bm0 + wm + i * 16 + (lane >> 4) * 4;
        float b = bias2[n];
        short4v pk;
#pragma unroll
        for (int r = 0; r < 4; ++r) pk[r] = (short)f2bf(acc[i][j][r] + b);
        *(short4v*)(vT + (size_t)e * (BATCH * SEQ_N) + rbase) = pk;
      }
    }
  }
}

// ---- lc_kernel: {colsumV (bid<512) | band logits 64x64 tiles} fused (896 blocks) ----
__global__ __launch_bounds__(256)
void lc_kernel(const unsigned short* __restrict__ vT,
               float* __restrict__ colsumV,
               const unsigned short* __restrict__ U,
               const unsigned short* __restrict__ Xb,
               const float* __restrict__ rho,
               float* __restrict__ Sband,              // [8192][192]
               const float* __restrict__ K1d)
{
  __shared__ unsigned short As[64 * 64];
  __shared__ unsigned short Bs[64 * 64];
  const int bid = blockIdx.x, tid = threadIdx.x;
  const int lane = tid & 63, wave = tid >> 6;

  if (bid < 512) {
    const int idx = bid * 4 + wave;     // 0..2047
    const int d = idx >> 1, b = idx & 1;
    const unsigned short* p = vT + (size_t)d * (BATCH * SEQ_N) + b * SEQ_N;
    float s = 0.f;
#pragma unroll
    for (int it = 0; it < 8; ++it) {
      short8 v = *(const short8*)(p + (size_t)(it * 512 + lane * 8));
#pragma unroll
      for (int e = 0; e < 8; ++e) s += bf2f((unsigned short)v[e]);
    }
#pragma unroll
    for (int o = 32; o; o >>= 1) s += __shfl_xor(s, o);
    if (lane == 0) colsumV[b * D_MODEL + d] = s;
    return;
  }

  const int u_  = bid - 512;             // 0..383
  const int bx  = u_ % 3;                // 64-col tile of the 192 window
  const int gz  = u_ / 3;                // 0..127
  const int g   = gz & 63;
  const int z   = gz >> 6;
  const int bm0 = g * 64;
  const int cb  = g * 64 - 64 + bx * 64; // col base; may be <0 or >=4096
  const int wm = (wave >> 1) * 32, wn = (wave & 1) * 32;

  const unsigned short* Ag = U  + (size_t)z * SEQ_N * D_MODEL;
  const unsigned short* Bg = Xb + (size_t)z * SEQ_N * D_MODEL;

  floatx4 acc[2][2] = {};
  for (int k0 = 0; k0 < D_MODEL; k0 += 64) {
#pragma unroll
    for (int t = 0; t < 2; ++t) {       // A tile [64][64]
      int bu  = wave * 64 + t * 256;
      int u   = bu + lane;
      int row = u >> 3;
      int c   = (u & 7) ^ (row & 7);
      const unsigned short* srcA = Ag + (size_t)(bm0 + row) * D_MODEL + k0 + c * 8;
      __builtin_amdgcn_global_load_lds((const __attribute__((address_space(1))) void*)srcA,
                                       (__attribute__((address_space(3))) void*)(As + bu * 8), 16, 0, 0);
    }
#pragma unroll
    for (int t = 0; t < 2; ++t) {       // B tile [64][64]; rows may be OOB (finite ws, masked in epi)
      int bu  = wave * 64 + t * 256;
      int u   = bu + lane;
      int row = u >> 3;
      int c   = (u & 7) ^ (row & 7);
      const unsigned short* srcB = Bg + (long)(cb + row) * D_MODEL + k0 + c * 8;
      __builtin_amdgcn_global_load_lds((const __attribute__((address_space(1))) void*)srcB,
                                       (__attribute__((address_space(3))) void*)(Bs + bu * 8), 16, 0, 0);
    }
    __syncthreads();
#pragma unroll
    for (int s = 0; s < 2; ++s) {
      short8 af[2], bf[2];
#pragma unroll
      for (int i = 0; i < 2; ++i) {
        int row = wm + i * 16 + (lane & 15);
        int pc  = (s * 4 + (lane >> 4)) ^ (row & 7);
        af[i] = *(const short8*)(As + row * 64 + pc * 8);
      }
#pragma unroll
      for (int j = 0; j < 2; ++j) {
        int row = wn + j * 16 + (lane & 15);
        int pc  = (s * 4 + (lane >> 4)) ^ (row & 7);
        bf[j] = *(const short8*)(Bs + row * 64 + pc * 8);
      }
#pragma unroll
      for (int i = 0; i < 2; ++i)
#pragma unroll
        for (int j = 0; j < 2; ++j)
          acc[i][j] = __builtin_amdgcn_mfma_f32_16x16x32_bf16(af[i], bf[j], acc[i][j], 0, 0, 0);
    }
    __syncthreads();
  }

  float* Cb = Sband + ((size_t)z * SEQ_N + bm0) * BAND + bx * 64;
#pragma unroll
  for (int i = 0; i < 2; ++i) {
    int rl0 = wm + i * 16 + (lane >> 4) * 4;
    float rr[4];
#pragma unroll
    for (int r = 0; r < 4; ++r) rr[r] = rho[(size_t)z * SEQ_N + bm0 + rl0 + r];
#pragma unroll
    for (int j = 0; j < 2; ++j) {
      int cl  = wn + j * 16 + (lane & 15);
#pragma unroll
      for (int r = 0; r < 4; ++r) {
        int col = cb + cl;
        int d = (bm0 + rl0 + r) - col; d = d < 0 ? -d : d;   // <= 127
        float v = ((unsigned)col < (unsigned)SEQ_N)
                    ? (acc[i][j][r] + rr[r]) * 0.03125f * K1d[d] : 0.f;
        Cb[(size_t)(rl0 + r) * BAND + cl] = v;
      }
    }
  }
}

// ---- sk_kernel: {band softmax (bid<2048) | writeK} fused (18432 blocks) ----
__global__ __launch_bounds__(256)
void sk_kernel(const float* __restrict__ Sband,
               float* __restrict__ attn,
               unsigned short* __restrict__ Pb,
               float* __restrict__ c_arr,
               float* __restrict__ Kout,
               const float* __restrict__ K1d)
{
  __shared__ float lds_e[4][BAND];
  const int bid = blockIdx.x, tid = threadIdx.x;
  const int lane = tid & 63, wave = tid >> 6;

  if (bid >= 2048) {
    // ---- writeK: K[i,j] = K1d[|i-j|] ----
    size_t t = (size_t)(bid - 2048) * 256 + tid;
    size_t f = t * 4;
    int i = (int)(f >> 12);
    int j = (int)(f & 4095);
    floatx4 v;
#pragma unroll
    for (int e = 0; e < 4; ++e) {
      int d = i - (j + e); d = d < 0 ? -d : d;
      v[e] = K1d[d];
    }
    __builtin_nontemporal_store(v, (floatx4*)(Kout + f));
    return;
  }

  const int gi = bid * 4 + wave;     // 0..8191
  const int ii = gi & (SEQ_N - 1);
  const int g  = ii >> 6;
  const int cbase = g * 64 - 64;
  const float* S = Sband + (size_t)gi * BAND;

  float sv[3];
  float m = 0.0f;                           // far logits are exactly 0
#pragma unroll
  for (int j = 0; j < 3; ++j) {
    int t = j * 64 + lane;
    int col = cbase + t;
    sv[j] = S[t];
    if ((unsigned)col < (unsigned)SEQ_N) m = fmaxf(m, sv[j]);
  }
#pragma unroll
  for (int o = 32; o; o >>= 1) m = fmaxf(m, __shfl_xor(m, o));

  float s = 0.f;
#pragma unroll
  for (int j = 0; j < 3; ++j) {
    int t = j * 64 + lane;
    int col = cbase + t;
    float e = ((unsigned)col < (unsigned)SEQ_N) ? __expf(sv[j] - m) : 0.f;
    sv[j] = e;
    s += e;
  }
#pragma unroll
  for (int o = 32; o; o >>= 1) s += __shfl_xor(s, o);

  int n_valid = BAND - ((g == 0) ? 64 : 0) - ((g == 63) ? 64 : 0);
  float efar  = __expf(-m);
  float denom = s + (float)(SEQ_N - n_valid) * efar;
  float inv   = 1.0f / denom;
  float c     = efar * inv;

  unsigned short* prow = Pb + (size_t)gi * BAND;
#pragma unroll
  for (int j = 0; j < 3; ++j) {
    int t = j * 64 + lane;
    float p = sv[j] * inv;
    lds_e[wave][t] = p;
    int col = cbase + t;
    prow[t] = ((unsigned)col < (unsigned)SEQ_N) ? f2bf(p - c) : (unsigned short)0;
  }
  if (lane == 0) c_arr[gi] = c;

  float* arow = attn + (size_t)gi * SEQ_N;
#pragma unroll
  for (int jj = 0; jj < 16; ++jj) {
    int col0 = jj * 256 + lane * 4;
    floatx4 o;
#pragma unroll
    for (int e = 0; e < 4; ++e) {
      int t = col0 + e - cbase;
      o[e] = ((unsigned)t < (unsigned)BAND) ? lds_e[wave][t] : c;
    }
    __builtin_nontemporal_store(o, (floatx4*)(arow + col0));
  }
}

// ---- band PV: out = (P-c) @ V_band + c * colsumV; K=192, BK=64 + XOR swizzle ----
__global__ __launch_bounds__(256)
void band_pv(const unsigned short* __restrict__ Pb,   // [8192][192]
             const unsigned short* __restrict__ vT,   // [1024][8192]
             const float* __restrict__ c_arr,         // [8192]
             const float* __restrict__ colsumV,       // [2][1024]
             float* __restrict__ outp)                // [2][4096][1024]
{
  __shared__ unsigned short As[64 * 64];
  __shared__ unsigned short Bs[128 * 64];
  const int tid = threadIdx.x, lane = tid & 63, wave = tid >> 6;
  const int bx = blockIdx.x;     // 0..7  d-block (128 cols)
  const int g  = blockIdx.y;     // 0..63 64-row group
  const int z  = blockIdx.z;
  const int bm0 = g * 64;
  const int bn0 = bx * 128;
  const int wm = (wave >> 1) * 32, wn = (wave & 1) * 64;

  const unsigned short* Ag = Pb + ((size_t)z * SEQ_N + bm0) * BAND;
  // B row d, band col t -> vT[d][z*4096 + g*64 - 64 + t]; +-64 overrun lands in
  // adjacent ws buffers (finite bf16, always multiplied by P==0).
  const unsigned short* Bg = vT + (long)z * SEQ_N + (long)bm0 - 64;

  floatx4 acc[2][4] = {};
  for (int k0 = 0; k0 < BAND; k0 += 64) {
#pragma unroll
    for (int t = 0; t < 2; ++t) {
      int bu  = wave * 64 + t * 256;
      int u   = bu + lane;
      int row = u >> 3;
      int c   = (u & 7) ^ (row & 7);
      const unsigned short* srcA = Ag + (size_t)row * BAND + k0 + c * 8;
      __builtin_amdgcn_global_load_lds((const __attribute__((address_space(1))) void*)srcA,
                                       (__attribute__((address_space(3))) void*)(As + bu * 8), 16, 0, 0);
    }
#pragma unroll
    for (int t = 0; t < 4; ++t) {
      int bu  = wave * 64 + t * 256;
      int u   = bu + lane;
      int row = u >> 3;
      int c   = (u & 7) ^ (row & 7);
      const unsigned short* srcB = Bg + (size_t)(bn0 + row) * (BATCH * SEQ_N) + k0 + c * 8;
      __builtin_amdgcn_global_load_lds((const __attribute__((address_space(1))) void*)srcB,
                                       (__attribute__((address_space(3))) void*)(Bs + bu * 8), 16, 0, 0);
    }
    __syncthreads();
#pragma unroll
    for (int s = 0; s < 2; ++s) {
      short8 af[2], bf[4];
#pragma unroll
      for (int i = 0; i < 2; ++i) {
        int row = wm + i * 16 + (lane & 15);
        int pc  = (s * 4 + (lane >> 4)) ^ (row & 7);
        af[i] = *(const short8*)(As + row * 64 + pc * 8);
      }
#pragma unroll
      for (int j = 0; j < 4; ++j) {
        int row = wn + j * 16 + (lane & 15);
        int pc  = (s * 4 + (lane >> 4)) ^ (row & 7);
        bf[j] = *(const short8*)(Bs + row * 64 + pc * 8);
      }
#pragma unroll
      for (int i = 0; i < 2; ++i)
#pragma unroll
        for (int j = 0; j < 4; ++j)
          acc[i][j] = __builtin_amdgcn_mfma_f32_16x16x32_bf16(af[i], bf[j], acc[i][j], 0, 0, 0);
    }
    __syncthreads();
  }

#pragma unroll
  for (int i = 0; i < 2; ++i) {
#pragma unroll
    for (int j = 0; j < 4; ++j) {
      int col   = bn0 + wn + j * 16 + (lane & 15);
      int rbase = bm0 + wm + i * 16 + (lane >> 4) * 4;
      float csv = colsumV[z * D_MODEL + col];
#pragma unroll
      for (int r = 0; r < 4; ++r) {
        int row = rbase + r;
        float o = acc[i][j][r] + c_arr[(size_t)z * SEQ_N + row] * csv;
        __builtin_nontemporal_store(o, outp + ((size_t)z * SEQ_N + row) * D_MODEL + col);
      }
    }
  }
}

// ---------------- fallback-path kernels (round-1 proven) ----------------
__global__ void k1d_kernel(float* __restrict__ K1d,
                           const float* __restrict__ alpha_p,
                           const float* __restrict__ lam_p) {
  int r = blockIdx.x * blockDim.x + threadIdx.x;
  if (r >= SEQ_N) return;
  float a   = fabsf(alpha_p[0]);
  float lam = fabsf(lam_p[0]);
  float rf  = (float)r;
  K1d[r] = powf(rf + 1e-4f, -a) * expf(-rf / lam);
}

__global__ __launch_bounds__(256) void writeK_kernel(float* __restrict__ Kout,
                                                     const float* __restrict__ K1d) {
  size_t t = (size_t)blockIdx.x * 256 + threadIdx.x;
  size_t f = t * 4;
  int i = (int)(f >> 12);
  int j = (int)(f & 4095);
  floatx4 v;
#pragma unroll
  for (int e = 0; e < 4; ++e) {
    int d = i - (j + e); d = d < 0 ? -d : d;
    v[e] = K1d[d];
  }
  __builtin_nontemporal_store(v, (floatx4*)(Kout + f));
}

#define BM 128
#define BN 128
#define BK 32

template<int ASRC, int BSRC, int EPI>
__global__ __launch_bounds__(256)
void gemm_bt(const void* __restrict__ Ap_, int lda, long sA,
             const void* __restrict__ Bp_, int ldb, long sB,
             void* __restrict__ Cp_, int ldc, long sC,
             int K, const float* __restrict__ bias,
             const float* __restrict__ K1d)
{
  __shared__ unsigned short As[BM * BK];
  __shared__ unsigned short Bs[BN * BK];
  const int tid  = threadIdx.x;
  const int lane = tid & 63;
  const int wave = tid >> 6;

  int gx = (int)gridDim.x, gy = (int)gridDim.y;
  int total = gx * gy * (int)gridDim.z;
  int flat  = (int)blockIdx.z * gx * gy + (int)blockIdx.y * gx + (int)blockIdx.x;
  int w     = (flat & 7) * (total >> 3) + (flat >> 3);
  int bx = w % gx;
  int t_ = w / gx;
  int by = t_ % gy;
  int z  = t_ / gy;

  const int bm0  = by * BM;
  const int bn0  = bx * BN;
  const int wm   = (wave >> 1) * 64;
  const int wn   = (wave & 1) * 64;

  floatx4 acc[4][4] = {};

  const unsigned short* Agb = (const unsigned short*)Ap_ + (size_t)z * (size_t)sA;
  const float*          Agf = (const float*)Ap_          + (size_t)z * (size_t)sA;
  const unsigned short* Bgb = (const unsigned short*)Bp_ + (size_t)z * (size_t)sB;
  const float*          Bgf = (const float*)Bp_          + (size_t)z * (size_t)sB;

  for (int k0 = 0; k0 < K; k0 += BK) {
    if constexpr (ASRC == 0) {
#pragma unroll
      for (int t = 0; t < 2; ++t) {
        int bu = wave * 64 + t * 256;
        int u  = bu + lane;
        const unsigned short* src = Agb + (size_t)(bm0 + (u >> 2)) * lda + k0 + (u & 3) * 8;
        __builtin_amdgcn_global_load_lds((const __attribute__((address_space(1))) void*)src,
                                         (__attribute__((address_space(3))) void*)(As + bu * 8),
                                         16, 0, 0);
      }
    } else {
#pragma unroll
      for (int t = 0; t < 2; ++t) {
        int u = tid + t * 256;
        const float* src = Agf + (size_t)(bm0 + (u >> 2)) * lda + k0 + (u & 3) * 8;
        floatx4 x0 = *(const floatx4*)src;
        floatx4 x1 = *(const floatx4*)(src + 4);
        short8 pk;
        pk[0] = (short)f2bf(x0[0]); pk[1] = (short)f2bf(x0[1]);
        pk[2] = (short)f2bf(x0[2]); pk[3] = (short)f2bf(x0[3]);
        pk[4] = (short)f2bf(x1[0]); pk[5] = (short)f2bf(x1[1]);
        pk[6] = (short)f2bf(x1[2]); pk[7] = (short)f2bf(x1[3]);
        *(short8*)(As + u * 8) = pk;
      }
    }
    if constexpr (BSRC == 0) {
#pragma unroll
      for (int t = 0; t < 2; ++t) {
        int bu = wave * 64 + t * 256;
        int u  = bu + lane;
        const unsigned short* src = Bgb + (size_t)(bn0 + (u >> 2)) * ldb + k0 + (u & 3) * 8;
        __builtin_amdgcn_global_load_lds((const __attribute__((address_space(1))) void*)src,
                                         (__attribute__((address_space(3))) void*)(Bs + bu * 8),
                                         16, 0, 0);
      }
    } else {
#pragma unroll
      for (int t = 0; t < 2; ++t) {
        int u = tid + t * 256;
        const float* src = Bgf + (size_t)(bn0 + (u >> 2)) * ldb + k0 + (u & 3) * 8;
        floatx4 x0 = *(const floatx4*)src;
        floatx4 x1 = *(const floatx4*)(src + 4);
        short8 pk;
        pk[0] = (short)f2bf(x0[0]); pk[1] = (short)f2bf(x0[1]);
        pk[2] = (short)f2bf(x0[2]); pk[3] = (short)f2bf(x0[3]);
        pk[4] = (short)f2bf(x1[0]); pk[5] = (short)f2bf(x1[1]);
        pk[6] = (short)f2bf(x1[2]); pk[7] = (short)f2bf(x1[3]);
        *(short8*)(Bs + u * 8) = pk;
      }
    }
    __syncthreads();

    short8 af[4], bf[4];
#pragma unroll
    for (int i = 0; i < 4; ++i)
      af[i] = *(const short8*)(As + (wm + i * 16 + (lane & 15)) * BK + (lane >> 4) * 8);
#pragma unroll
    for (int j = 0; j < 4; ++j)
      bf[j] = *(const short8*)(Bs + (wn + j * 16 + (lane & 15)) * BK + (lane >> 4) * 8);
#pragma unroll
    for (int i = 0; i < 4; ++i)
#pragma unroll
      for (int j = 0; j < 4; ++j)
        acc[i][j] = __builtin_amdgcn_mfma_f32_16x16x32_bf16(af[i], bf[j], acc[i][j], 0, 0, 0);
    __syncthreads();
  }

  const int col0 = bn0 + wn;
  const int row0 = bm0 + wm;
#pragma unroll
  for (int i = 0; i < 4; ++i) {
#pragma unroll
    for (int j = 0; j < 4; ++j) {
      int col   = col0 + j * 16 + (lane & 15);
      int rbase = row0 + i * 16 + (lane >> 4) * 4;
      if constexpr (EPI == 0) {
        unsigned short* C = (unsigned short*)Cp_ + (size_t)z * (size_t)sC;
        float b = bias[col];
#pragma unroll
        for (int r = 0; r < 4; ++r)
          C[(size_t)(rbase + r) * ldc + col] = f2bf(acc[i][j][r] + b);
      } else if constexpr (EPI == 1) {
        unsigned short* C = (unsigned short*)Cp_ + (size_t)z * (size_t)sC;
#pragma unroll
        for (int r = 0; r < 4; ++r)
          C[(size_t)(rbase + r) * ldc + col] = f2bf(acc[i][j][r] + bias[rbase + r]);
      } else if constexpr (EPI == 2) {
        float* C = (float*)Cp_ + (size_t)z * (size_t)sC;
#pragma unroll
        for (int r = 0; r < 4; ++r) {
          int row = rbase + r;
          int d = row - col; d = d < 0 ? -d : d;
          C[(size_t)row * ldc + col] = acc[i][j][r] * 0.03125f * K1d[d];
        }
      } else {
        float* C = (float*)Cp_ + (size_t)z * (size_t)sC;
#pragma unroll
        for (int r = 0; r < 4; ++r)
          C[(size_t)(rbase + r) * ldc + col] = acc[i][j][r];
      }
    }
  }
}

__global__ __launch_bounds__(256)
void softmax_kernel(float* __restrict__ attn) {
  const int tid = threadIdx.x;
  float* p = attn + (size_t)blockIdx.x * SEQ_N;
  floatx4* p4 = (floatx4*)p;
  floatx4 x[4];
  float m = -3.402823466e+38f;
#pragma unroll
  for (int c = 0; c < 4; ++c) {
    x[c] = p4[tid + c * 256];
    m = fmaxf(m, fmaxf(fmaxf(x[c][0], x[c][1]), fmaxf(x[c][2], x[c][3])));
  }
#pragma unroll
  for (int o = 32; o; o >>= 1) m = fmaxf(m, __shfl_xor(m, o));
  __shared__ float redm[4], reds[4];
  if ((tid & 63) == 0) redm[tid >> 6] = m;
  __syncthreads();
  m = fmaxf(fmaxf(redm[0], redm[1]), fmaxf(redm[2], redm[3]));
  float s = 0.f;
#pragma unroll
  for (int c = 0; c < 4; ++c)
#pragma unroll
    for (int e = 0; e < 4; ++e) {
      float t = __expf(x[c][e] - m);
      x[c][e] = t;
      s += t;
    }
#pragma unroll
  for (int o = 32; o; o >>= 1) s += __shfl_xor(s, o);
  if ((tid & 63) == 0) reds[tid >> 6] = s;
  __syncthreads();
  s = reds[0] + reds[1] + reds[2] + reds[3];
  float inv = 1.0f / s;
#pragma unroll
  for (int c = 0; c < 4; ++c) {
    floatx4 y;
#pragma unroll
    for (int e = 0; e < 4; ++e) y[e] = x[c][e] * inv;
    p4[tid + c * 256] = y;
  }
}

extern "C" void kernel_launch(void* const* d_in, const int* in_sizes, int n_in,
                              void* d_out, int out_size, void* d_ws, size_t ws_size,
                              hipStream_t stream) {
  const float* x     = (const float*)d_in[0];
  const float* Wq    = (const float*)d_in[1];
  const float* bq    = (const float*)d_in[2];
  const float* Wk    = (const float*)d_in[3];
  const float* bk    = (const float*)d_in[4];
  const float* Wv    = (const float*)d_in[5];
  const float* bv    = (const float*)d_in[6];
  const float* alpha = (const float*)d_in[7];
  const float* lam   = (const float*)d_in[8];

  float* outp  = (float*)d_out;
  float* attnp = outp + (size_t)BATCH * SEQ_N * D_MODEL;
  float* Kp    = attnp + (size_t)BATCH * SEQ_N * SEQ_N;

  char* ws = (char*)d_ws;
  float* K1d = (float*)ws;                                  // 16 KB
  unsigned short* vT   = (unsigned short*)(ws + 16384);     // [1024][8192]
  unsigned short* xb   = vT + NELEM;                        // [8192][1024]
  unsigned short* ub   = xb + NELEM;                        // [8192][1024]  u' bf16
  unsigned short* wqT  = ub + NELEM;                        // [1024][1024]
  unsigned short* wkT  = wqT + (size_t)D_MODEL * D_MODEL;   // [1024][1024]
  unsigned short* Bcat2 = wkT + (size_t)D_MODEL * D_MODEL;  // [2048][1024]: Mt | Wv
  float* Sband   = (float*)(Bcat2 + (size_t)2 * D_MODEL * D_MODEL); // [8192][192]
  unsigned short* Pb = (unsigned short*)(Sband + (size_t)BATCH * SEQ_N * BAND);
  float* c_arr   = (float*)(Pb + (size_t)BATCH * SEQ_N * BAND);     // [8192]
  float* colsumV = c_arr + (size_t)BATCH * SEQ_N;                   // [2][1024]
  float* bias2   = colsumV + (size_t)BATCH * D_MODEL;               // [2048]
  float* wqv     = bias2 + 2 * D_MODEL;                             // [1024]
  float* rho     = wqv + D_MODEL;                                   // [8192]

  size_t need = (size_t)((char*)(rho + BATCH * SEQ_N) - ws);
  const bool fast = ws_size >= need;

  if (fast) {
    fused_prep<<<5140, 256, 0, stream>>>(x, Wq, Wk, Wv, bv, alpha, lam,
                                         xb, Bcat2, wqT, wkT, bias2, K1d);
    wg_kernel<<<768, 256, 0, stream>>>(wkT, wqT, bq, bk, Bcat2, bias2, wqv);
    uvr_kernel<<<3072, 256, 0, stream>>>(xb, Bcat2, bias2, ub, vT, wqv, bq, bk, rho);
    lc_kernel<<<896, 256, 0, stream>>>(vT, colsumV, ub, xb, rho, Sband, K1d);
    sk_kernel<<<18432, 256, 0, stream>>>(Sband, attnp, Pb, c_arr, Kp, K1d);
    band_pv<<<dim3(D_MODEL / 128, SEQ_N / 64, BATCH), 256, 0, stream>>>(
        Pb, vT, c_arr, colsumV, outp);
  } else {
    // fallback: round-1 proven path (qb->xb slot, kb->ub slot)
    unsigned short* qb = xb;
    unsigned short* kb = ub;
    k1d_kernel<<<16, 256, 0, stream>>>(K1d, alpha, lam);
    writeK_kernel<<<(SEQ_N * SEQ_N / 4) / 256, 256, 0, stream>>>(Kp, K1d);
    gemm_bt<1, 1, 0><<<dim3(D_MODEL / BN, BATCH * SEQ_N / BM, 1), 256, 0, stream>>>(
        x, D_MODEL, 0, Wq, D_MODEL, 0, qb, D_MODEL, 0, D_MODEL, bq, nullptr);
    gemm_bt<1, 1, 0><<<dim3(D_MODEL / BN, BATCH * SEQ_N / BM, 1), 256, 0, stream>>>(
        x, D_MODEL, 0, Wk, D_MODEL, 0, kb, D_MODEL, 0, D_MODEL, bk, nullptr);
    gemm_bt<1, 1, 1><<<dim3(BATCH * SEQ_N / BN, D_MODEL / BM, 1), 256, 0, stream>>>(
        Wv, D_MODEL, 0, x, D_MODEL, 0, vT, BATCH * SEQ_N, 0, D_MODEL, bv, nullptr);
    gemm_bt<0, 0, 2><<<dim3(SEQ_N / BN, SEQ_N / BM, BATCH), 256, 0, stream>>>(
        qb, D_MODEL, (long)SEQ_N * D_MODEL, kb, D_MODEL, (long)SEQ_N * D_MODEL,
        attnp, SEQ_N, (long)SEQ_N * SEQ_N, D_MODEL, nullptr, K1d);
    softmax_kernel<<<BATCH * SEQ_N, 256, 0, stream>>>(attnp);
    gemm_bt<1, 0, 3><<<dim3(D_MODEL / BN, SEQ_N / BM, BATCH), 256, 0, stream>>>(
        attnp, SEQ_N, (long)SEQ_N * SEQ_N, vT, BATCH * SEQ_N, (long)SEQ_N,
        outp, D_MODEL, (long)SEQ_N * D_MODEL, SEQ_N, nullptr, nullptr);
  }
}